// Round 10
// baseline (502.182 us; speedup 1.0000x reference)
//
#include <hip/hip_runtime.h>
#include <hip/hip_bf16.h>
#include <math.h>

// Problem constants
#define B_  4
#define T_  8192
#define H_  1024
#define NHEAD 16
#define DH  64
#define BT  (B_*T_)   // 32768 rows

typedef __attribute__((ext_vector_type(8))) short bf16x8;
typedef __attribute__((ext_vector_type(4))) float f32x4;
typedef __attribute__((ext_vector_type(2))) float f32x2;
typedef __attribute__((ext_vector_type(2))) unsigned short u16x2;
typedef __attribute__((ext_vector_type(4))) unsigned short u16x4;
typedef __attribute__((ext_vector_type(8))) unsigned short u16x8;

static __device__ __forceinline__ float bf2f(unsigned short u) {
  union { unsigned int i; float f; } x; x.i = ((unsigned int)u) << 16; return x.f;
}
static __device__ __forceinline__ unsigned short f2bf(float f) {
  union { float f; unsigned int i; } x; x.f = f;
  unsigned int r = x.i + 0x7fffu + ((x.i >> 16) & 1u);  // RNE
  return (unsigned short)(r >> 16);
}

#define GL2LDS(gptr, sptr) \
  __builtin_amdgcn_global_load_lds((const __attribute__((address_space(1))) void*)(gptr), \
                                   (__attribute__((address_space(3))) void*)(sptr), 16, 0, 0)

#define BAR() do { asm volatile("" ::: "memory"); __builtin_amdgcn_s_barrier(); \
                   asm volatile("" ::: "memory"); } while (0)

// ---------------------------------------------------------------- cvt fp32->bf16 (weights only)
__global__ void cvt_kernel(const float* __restrict__ in, unsigned short* __restrict__ out, int n4) {
  int i = blockIdx.x * blockDim.x + threadIdx.x;
  int stride = gridDim.x * blockDim.x;
  for (int idx = i; idx < n4; idx += stride) {
    float4 v = reinterpret_cast<const float4*>(in)[idx];
    u16x4 o;
    o.x = f2bf(v.x); o.y = f2bf(v.y); o.z = f2bf(v.z); o.w = f2bf(v.w);
    reinterpret_cast<u16x4*>(out)[idx] = o;
  }
}

// ---------------------------------------------------------------- 128x128 high-occupancy GEMM, fused fp32 A
// C[M,N] = cvt(A_f32)[M,K]*B[N,K]^T + bias ; M=32768, N=K=1024.
// BM=BN=128, BK=32, 4 waves (2Mx2N of 64x64), LDS 32KB (2 buf x (A 8KB +
// B 8KB)) -> ~3 blocks/CU. Co-resident blocks hide vmcnt/barrier stalls
// (m114/m97 mechanism) that killed the 1-block/CU 256^2 variants.
// SWIZZLE: byte ^= ((row>>1)&3)<<4 (64B rows). A via swizzled ds_write addr;
// B via pre-swizzled global source col; frag reads XOR the same key.
// r9 BUG FIXED HERE: B source key is (sr2>>1)&3 = (lane>>3)&3, NOT
// (lane>>2)&3 -- one-bit-off key mispaired B's k-chunks (absmax 4.7e-3).
// vmcnt chain: invariant entering tile t: stB(t+1)=2 + A32(t+2)=4 = 6.
// Tile t: BAR; +stB(t+2)=8; vmcnt(2) drains stB(t+1)+A32(t+2); writeA;
// issueA32(t+3) -> 6; lgkm0; BAR. Tails: t=29 no issue; t=30 vmcnt(0).
// grid = (8,256) = 2048 blocks, XCD-bijective swizzle (2048%8==0).
__global__ __launch_bounds__(256, 3) void gemm128f(
    const float* __restrict__ A,
    const unsigned short* __restrict__ Bm,
    const float* __restrict__ bias,
    unsigned short* __restrict__ C) {
  const int K = 1024, N = 1024;
  __shared__ char lds[32768];
  const int tid = threadIdx.x, lane = tid & 63, wid = tid >> 6;
  const int orig = blockIdx.y * 8 + blockIdx.x;
  const int swz  = (orig & 7) * 256 + (orig >> 3);
  const int bm = (swz >> 3) * 128, bn = (swz & 7) * 128;
  const int wm = (wid >> 1) * 64, wn = (wid & 1) * 64;

  // A fp32 staging: thread covers 64B (16 f32) of row r, col-half ch.
  const int r_  = tid >> 1;                 // 0..127
  const int ch  = (tid & 1) * 16;           // f32 col base within BK=32
  const float* gA32 = A + (size_t)(bm + r_) * K + ch;
  const int awbase = r_ * 64;
  const int awswz  = ((r_ >> 1) & 3) << 4;

  // B staging via gload_lds: linear dest row sr2, pre-swizzled source col.
  // key = (sr2>>1)&3 = (lane>>3)&3  [r9 fix]
  const int sr2  = wid * 16 + (lane >> 2);  // 0..63 (+64 on round 2)
  const int scol = ((lane & 3) * 8) ^ (((lane >> 3) & 3) << 3);
  const unsigned short* gB = Bm + (size_t)(bn + sr2) * K + scol;
  const int dstw = wid * 1024;

  // fragment reads: row = base + (lane&15); col = ((lane>>4)*16) ^ fswz
  const int fswz = (((lane & 15) >> 1) & 3) << 4;
  const int kc   = ((lane >> 4) * 16) ^ fswz;

  f32x4 acc[4][4];
#pragma unroll
  for (int nn = 0; nn < 4; ++nn) {
    float bv = bias[bn + wn + nn * 16 + (lane & 15)];
    f32x4 sp = {bv, bv, bv, bv};
#pragma unroll
    for (int mm = 0; mm < 4; ++mm) acc[mm][nn] = sp;
  }

  f32x4 ar[4];      // in-flight A fp32 (16 regs)
  bf16x8 aF[4], bF[4];

  auto issueA32 = [&](int kt) {
    const float* g = gA32 + kt * 32;
#pragma unroll
    for (int j = 0; j < 4; ++j) ar[j] = *(const f32x4*)(g + j * 4);
  };
  auto writeA = [&](int buf) {
#pragma unroll
    for (int h = 0; h < 2; ++h) {
      u16x8 o;
#pragma unroll
      for (int j = 0; j < 4; ++j) {
        o[j]     = f2bf(ar[2 * h][j]);
        o[4 + j] = f2bf(ar[2 * h + 1][j]);
      }
      *(u16x8*)(lds + buf * 16384 + awbase + ((ch * 2 + h * 16) ^ awswz)) = o;
    }
  };
  auto stB = [&](int buf, int kt) {          // 2 gload_lds
    char* d = lds + buf * 16384 + 8192 + dstw;
    const unsigned short* g = gB + kt * 32;
    GL2LDS(g, d);
    GL2LDS(g + (size_t)64 * K, d + 4096);
  };
  auto loadFrags = [&](int buf) {
#pragma unroll
    for (int f = 0; f < 4; ++f)
      aF[f] = *(const bf16x8*)(lds + buf * 16384 + (wm + f * 16 + (lane & 15)) * 64 + kc);
#pragma unroll
    for (int f = 0; f < 4; ++f)
      bF[f] = *(const bf16x8*)(lds + buf * 16384 + 8192 + (wn + f * 16 + (lane & 15)) * 64 + kc);
  };
  auto mfma16 = [&]() {
    __builtin_amdgcn_s_setprio(1);
#pragma unroll
    for (int mm = 0; mm < 4; ++mm)
#pragma unroll
      for (int nn = 0; nn < 4; ++nn)
        acc[mm][nn] = __builtin_amdgcn_mfma_f32_16x16x32_bf16(aF[mm], bF[nn], acc[mm][nn], 0, 0, 0);
    __builtin_amdgcn_s_setprio(0);
  };

  // prologue: tiles 0,1 staged; ar <- tile 2
  issueA32(0);
  asm volatile("s_waitcnt vmcnt(0)" ::: "memory");
  writeA(0);
  issueA32(1);                               // 4 outstanding
  stB(0, 0); stB(1, 1);                      // -> 8
  asm volatile("s_waitcnt vmcnt(4)" ::: "memory");   // drains A32(1)
  writeA(1);
  issueA32(2);                               // 4 + 4 = 8
  asm volatile("s_waitcnt vmcnt(6)" ::: "memory");   // drains stB(0); leaves stB(1)+A32(2)=6
  asm volatile("s_waitcnt lgkmcnt(0)" ::: "memory");
  BAR();

  // K-tiles 0..28 (full), 29/30/31 peeled
#define KBODY(t, STB_, DOW, WSTR, DOWRITE, DOISSUE)           \
  {                                                           \
    const int b_ = (t) & 1;                                   \
    loadFrags(b_);                                            \
    mfma16();                                                 \
    BAR();                                                    \
    if (STB_) stB(b_, (t) + 2);                               \
    if (DOW) { asm volatile("s_waitcnt vmcnt(" WSTR ")" ::: "memory"); } \
    if (DOWRITE) writeA(b_);                                  \
    if (DOISSUE) issueA32((t) + 3);                           \
    asm volatile("s_waitcnt lgkmcnt(0)" ::: "memory");        \
    BAR();                                                    \
  }

  for (int t = 0; t < 29; ++t) KBODY(t, 1, 1, "2", 1, 1)
  KBODY(29, 1, 1, "2", 1, 0)
  KBODY(30, 0, 1, "0", 0, 0)
  {
    loadFrags(1);
    mfma16();
  }
#undef KBODY

  // epilogue: C write (r2-verified mapping)
  const int crow = bm + wm + (lane >> 4) * 4;
  const int ccol = bn + wn + (lane & 15);
#pragma unroll
  for (int mm = 0; mm < 4; ++mm)
#pragma unroll
    for (int j = 0; j < 4; ++j) {
      unsigned short* cp = C + (size_t)(crow + mm * 16 + j) * N + ccol;
#pragma unroll
      for (int nn = 0; nn < 4; ++nn) cp[nn * 16] = f2bf(acc[mm][nn][j]);
    }
}

// ---------------------------------------------------------------- phase1 (MFMA): U-partials + colsum
__global__ __launch_bounds__(256, 2) void phase1(
    const unsigned short* __restrict__ Pk,
    const unsigned short* __restrict__ Pv,
    const float* __restrict__ mask_attn,
    float* __restrict__ Upart,     // [8][64][64][64]
    float* __restrict__ cspart) {  // [8][64][64]
  const int chunk = blockIdx.x;
  const int nh = blockIdx.y;
  const int n = nh >> 4, h = nh & 15;
  const int tid = threadIdx.x, lane = tid & 63, wid = tid >> 6;
  __shared__ __align__(16) unsigned short ekT[64 * 256];  // 32 KB
  __shared__ __align__(16) unsigned short vpT[64 * 256];  // 32 KB

  f32x4 acc[5];
#pragma unroll
  for (int i = 0; i < 5; ++i) acc[i] = (f32x4){0.f, 0.f, 0.f, 0.f};
  bf16x8 ones;
#pragma unroll
  for (int j = 0; j < 8; ++j) ones[j] = (short)0x3f80;

  const int isV = tid >> 7;
  const int slot0 = tid & 127;
  const unsigned short* src = isV ? Pv : Pk;
  unsigned short* dstT = isV ? vpT : ekT;

  const int arow = wid * 16 + (lane & 15);
  const int aswz = ((arow & 7) ^ ((arow >> 3) & 7)) << 4;

  for (int stage = 0; stage < 4; ++stage) {
    if (stage) __syncthreads();
#pragma unroll
    for (int r = 0; r < 2; ++r) {
      const int slot = slot0 + r * 128;
      const int toct = slot >> 3;
      const int d0   = (slot & 7) * 8;
      const int tbase = chunk * 1024 + stage * 256 + toct * 8;
      u16x8 in[8];
#pragma unroll
      for (int s = 0; s < 8; ++s)
        in[s] = *(const u16x8*)(src + (size_t)(n * T_ + tbase + s) * H_ + h * DH + d0);
      if (!isV) {
#pragma unroll
        for (int s = 0; s < 8; ++s) {
          const float madd = -10000.f * (1.f - mask_attn[n * T_ + tbase + s]);
          u16x8 o;
#pragma unroll
          for (int j = 0; j < 8; ++j) o[j] = f2bf(__expf(bf2f(in[s][j]) + madd));
          in[s] = o;
        }
      }
#pragma unroll
      for (int i = 0; i < 8; ++i) {
        u16x8 o;
#pragma unroll
        for (int s = 0; s < 8; ++s) o[s] = in[s][i];
        const int d = d0 + i;
        const int boff = (toct * 16) ^ (((d & 7) ^ ((d >> 3) & 7)) << 4);
        *(u16x8*)((char*)dstT + d * 512 + boff) = o;
      }
    }
    __syncthreads();
#pragma unroll
    for (int kk = 0; kk < 8; ++kk) {
      const int koff = kk * 64 + (lane >> 4) * 16;
      bf16x8 af = *(const bf16x8*)((const char*)ekT + arow * 512 + (koff ^ aswz));
      acc[4] = __builtin_amdgcn_mfma_f32_16x16x32_bf16(af, ones, acc[4], 0, 0, 0);
#pragma unroll
      for (int nn = 0; nn < 4; ++nn) {
        const int brow = nn * 16 + (lane & 15);
        const int bswz = ((brow & 7) ^ ((brow >> 3) & 7)) << 4;
        bf16x8 bf_ = *(const bf16x8*)((const char*)vpT + brow * 512 + (koff ^ bswz));
        acc[nn] = __builtin_amdgcn_mfma_f32_16x16x32_bf16(af, bf_, acc[nn], 0, 0, 0);
      }
    }
  }

  const int d = wid * 16 + (lane >> 4) * 4;
  const int e = lane & 15;
  float* up = Upart + ((size_t)(chunk * 64 + nh) * 64) * 64;
#pragma unroll
  for (int nn = 0; nn < 4; ++nn)
#pragma unroll
    for (int j = 0; j < 4; ++j)
      up[(size_t)(d + j) * 64 + nn * 16 + e] = acc[nn][j];
  if (e == 0)
#pragma unroll
    for (int j = 0; j < 4; ++j)
      cspart[((size_t)chunk * 64 + nh) * 64 + d + j] = acc[4][j];
}

// ---------------------------------------------------------------- ctx build
__global__ void ctxbuild(const float* __restrict__ Upart,
                         const float* __restrict__ cspart,
                         unsigned short* __restrict__ ctxT) {  // [64 nh][64 e][64 d]
  const int nh = blockIdx.x, tid = threadIdx.x;
  __shared__ float cs[64];
  if (tid < 64) {
    float s = 0;
    for (int c = 0; c < 8; ++c) s += cspart[((size_t)c * 64 + nh) * 64 + tid];
    cs[tid] = s;
  }
  __syncthreads();
  const int d0 = (tid >> 4) * 4, e0 = (tid & 15) * 4;
#pragma unroll
  for (int i = 0; i < 4; ++i) {
    const float inv = 0.125f / cs[d0 + i];   // 1/(sqrt(64)*colsum)
#pragma unroll
    for (int j = 0; j < 4; ++j) {
      float s = 0;
      for (int c = 0; c < 8; ++c)
        s += Upart[((size_t)(c * 64 + nh) * 64 + d0 + i) * 64 + e0 + j];
      ctxT[((size_t)nh * 64 + (e0 + j)) * 64 + (d0 + i)] = f2bf(s * inv);
    }
  }
}

// ---------------------------------------------------------------- out: softmax_feat(qp) @ ctx
__global__ __launch_bounds__(256) void outk(
    const unsigned short* __restrict__ Pq,
    const unsigned short* __restrict__ ctxT,
    float* __restrict__ Out) {
  const int tb = blockIdx.x;
  const int nh = blockIdx.y;
  const int n = nh >> 4, h = nh & 15;
  const int tid = threadIdx.x, lane = tid & 63, wid = tid >> 6;
  __shared__ unsigned short sp[128][72];

  bf16x8 breg[2][4];
#pragma unroll
  for (int ks = 0; ks < 2; ++ks)
#pragma unroll
    for (int nn = 0; nn < 4; ++nn)
      breg[ks][nn] = *(const bf16x8*)(ctxT + ((size_t)nh * 64 + nn * 16 + (lane & 15)) * 64
                                      + ks * 32 + (lane >> 4) * 8);

  const int r = tid >> 1, half = tid & 1;
  const int t0 = tb * 128;
  const size_t qoff = (size_t)(n * T_ + t0 + r) * H_ + h * DH + half * 32;
  u16x8 qv[4];
#pragma unroll
  for (int s = 0; s < 4; ++s) qv[s] = *(const u16x8*)(Pq + qoff + s * 8);
  float e[32]; float sum = 0.f;
#pragma unroll
  for (int s = 0; s < 4; ++s)
#pragma unroll
    for (int j = 0; j < 8; ++j) { float x = __expf(bf2f(qv[s][j])); e[s * 8 + j] = x; sum += x; }
  sum += __shfl_xor(sum, 1);
  const float inv = 1.f / sum;
#pragma unroll
  for (int s = 0; s < 4; ++s) {
    u16x8 pb;
#pragma unroll
    for (int j = 0; j < 8; ++j) pb[j] = f2bf(e[s * 8 + j] * inv);
    *(u16x8*)&sp[r][half * 32 + s * 8] = pb;
  }
  __syncthreads();

  f32x4 acc[2][4];
  f32x4 z = {0.f, 0.f, 0.f, 0.f};
#pragma unroll
  for (int mm = 0; mm < 2; ++mm)
#pragma unroll
    for (int nn = 0; nn < 4; ++nn) acc[mm][nn] = z;
  const int wm = wid * 32;
#pragma unroll
  for (int ks = 0; ks < 2; ++ks) {
    bf16x8 av[2];
#pragma unroll
    for (int mm = 0; mm < 2; ++mm)
      av[mm] = *(const bf16x8*)((const char*)&sp[0][0]
               + (wm + mm * 16 + (lane & 15)) * 144 + ks * 64 + (lane >> 4) * 16);
#pragma unroll
    for (int mm = 0; mm < 2; ++mm)
#pragma unroll
      for (int nn = 0; nn < 4; ++nn)
        acc[mm][nn] = __builtin_amdgcn_mfma_f32_16x16x32_bf16(av[mm], breg[ks][nn], acc[mm][nn], 0, 0, 0);
  }

#pragma unroll
  for (int mm = 0; mm < 2; ++mm)
#pragma unroll
    for (int j = 0; j < 4; ++j) {
      const int row = t0 + wm + mm * 16 + (lane >> 4) * 4 + j;
      float* op = Out + ((size_t)n * T_ + row) * H_ + h * DH + (lane & 15);
#pragma unroll
      for (int nn = 0; nn < 4; ++nn) op[nn * 16] = acc[mm][nn][j];
    }
}

// ---------------------------------------------------------------- launch
extern "C" void kernel_launch(void* const* d_in, const int* in_sizes, int n_in,
                              void* d_out, int out_size, void* d_ws, size_t ws_size,
                              hipStream_t stream) {
  const float* q  = (const float*)d_in[0];
  const float* k  = (const float*)d_in[1];
  const float* v  = (const float*)d_in[2];
  // d_in[3] = mask_q: per-row constant before feature-dim softmax -> provably a no-op
  const float* mask_attn = (const float*)d_in[4];
  const float* Wq = (const float*)d_in[5];
  const float* bq = (const float*)d_in[6];
  const float* Wk = (const float*)d_in[7];
  const float* bk = (const float*)d_in[8];
  const float* Wv = (const float*)d_in[9];
  const float* bv = (const float*)d_in[10];
  float* out = (float*)d_out;

  char* ws = (char*)d_ws;
  size_t off = 0;
  unsigned short* Wb = (unsigned short*)(ws + off); off += (size_t)3 * H_ * H_ * 2;   // 6 MB
  unsigned short* Pq = (unsigned short*)(ws + off); off += (size_t)BT * H_ * 2;
  unsigned short* Pk = (unsigned short*)(ws + off); off += (size_t)BT * H_ * 2;
  unsigned short* Pv = (unsigned short*)(ws + off); off += (size_t)BT * H_ * 2;
  float* Upart  = (float*)(ws + off); off += (size_t)8 * 64 * 64 * 64 * 4;            // 8 MB
  float* cspart = (float*)(ws + off); off += (size_t)8 * 64 * 64 * 4;
  unsigned short* ctxT = (unsigned short*)(ws + off); off += (size_t)64 * 64 * 64 * 2;

  dim3 blk(256);
  const int nW4 = H_ * H_ / 4;
  cvt_kernel<<<dim3(512), blk, 0, stream>>>(Wq, Wb + 0 * H_ * H_, nW4);
  cvt_kernel<<<dim3(512), blk, 0, stream>>>(Wk, Wb + 1 * H_ * H_, nW4);
  cvt_kernel<<<dim3(512), blk, 0, stream>>>(Wv, Wb + 2 * H_ * H_, nW4);

  dim3 ggrid(8, 256);   // N/128, M/128 (gemm128f swizzle assumes this shape)
  gemm128f<<<ggrid, blk, 0, stream>>>(k, Wb + 1 * H_ * H_, bk, Pk);
  gemm128f<<<ggrid, blk, 0, stream>>>(v, Wb + 2 * H_ * H_, bv, Pv);
  gemm128f<<<ggrid, blk, 0, stream>>>(q, Wb + 0 * H_ * H_, bq, Pq);

  phase1<<<dim3(8, 64), blk, 0, stream>>>(Pk, Pv, mask_attn, Upart, cspart);
  ctxbuild<<<dim3(64), blk, 0, stream>>>(Upart, cspart, ctxT);
  outk<<<dim3(64, 64), blk, 0, stream>>>(Pq, ctxT, out);
}

// Round 11
// 414.792 us; speedup vs baseline: 1.2107x; 1.2107x over previous
//
#include <hip/hip_runtime.h>
#include <hip/hip_bf16.h>
#include <math.h>

// Problem constants
#define B_  4
#define T_  8192
#define H_  1024
#define NHEAD 16
#define DH  64
#define BT  (B_*T_)   // 32768 rows

typedef __attribute__((ext_vector_type(8))) short bf16x8;
typedef __attribute__((ext_vector_type(4))) float f32x4;
typedef __attribute__((ext_vector_type(2))) float f32x2;
typedef __attribute__((ext_vector_type(2))) unsigned short u16x2;
typedef __attribute__((ext_vector_type(4))) unsigned short u16x4;
typedef __attribute__((ext_vector_type(8))) unsigned short u16x8;

static __device__ __forceinline__ float bf2f(unsigned short u) {
  union { unsigned int i; float f; } x; x.i = ((unsigned int)u) << 16; return x.f;
}
static __device__ __forceinline__ unsigned short f2bf(float f) {
  union { float f; unsigned int i; } x; x.f = f;
  unsigned int r = x.i + 0x7fffu + ((x.i >> 16) & 1u);  // RNE
  return (unsigned short)(r >> 16);
}

#define GL2LDS(gptr, sptr) \
  __builtin_amdgcn_global_load_lds((const __attribute__((address_space(1))) void*)(gptr), \
                                   (__attribute__((address_space(3))) void*)(sptr), 16, 0, 0)

#define BAR() do { asm volatile("" ::: "memory"); __builtin_amdgcn_s_barrier(); \
                   asm volatile("" ::: "memory"); } while (0)

// ---------------------------------------------------------------- cvt fp32->bf16 (weights only)
__global__ void cvt_kernel(const float* __restrict__ in, unsigned short* __restrict__ out, int n4) {
  int i = blockIdx.x * blockDim.x + threadIdx.x;
  int stride = gridDim.x * blockDim.x;
  for (int idx = i; idx < n4; idx += stride) {
    float4 v = reinterpret_cast<const float4*>(in)[idx];
    u16x4 o;
    o.x = f2bf(v.x); o.y = f2bf(v.y); o.z = f2bf(v.z); o.w = f2bf(v.w);
    reinterpret_cast<u16x4*>(out)[idx] = o;
  }
}

// ---------------------------------------------------------------- 256x256 GEMM, fp32-A-in-LDS, DMA-only staging
// C[M,N] = cvt(A_f32)[M,K]*B[N,K]^T + bias ; M=32768, N=K=1024.
// r11 design: BM=BN=256, BK=32, 8 waves (2Mx4N, 128x64/wave).
// A staged as RAW FP32 via global_load_lds (no reg round-trip, no ds_write,
// no lgkm on staging path) -> cvt to bf16 at FRAGMENT READ time via
// v_cvt_pk_bf16_f32 (4 asm ops/frag). B bf16 via gload_lds as before.
// All staging = 6 fire-and-forget DMAs/tile (A 4 + B 2); ONE vmcnt(6)/tile
// (a full K-tile of slack); 2 barriers/tile. LDS 96KB = 2 x (A32K + B16K).
// SWIZZLES (both-sides involutions, rule #21):
//  A (128B rows): chunk c of row r holds source chunk c^(r&7); staging source
//    f32 col = ((lane&7)*4)^(((lane>>3)&7)<<2); read byte col ^((lane&7)<<4).
//  B (64B rows):  key (r>>1)&3; staging source col ((lane&3)*8)^(((lane>>3)&3)<<3)
//    [r10-verified]; read byte col ^((((lane&15)>>1)&3)<<4).
// vmcnt chain: entering tile t outstanding = tile(t+1)'s 6. Tile t: compute;
// BAR; stage t+2 (ordered stA then stB) -> 12; vmcnt(6) drains t+1; BAR.
// Tails: t=30 vmcnt(0); t=31 compute only.
// grid = 512 blocks, XCD-bijective swizzle (512%8==0).
__global__ __launch_bounds__(512, 2) void gemm256d(
    const float* __restrict__ A,
    const unsigned short* __restrict__ Bm,
    const float* __restrict__ bias,
    unsigned short* __restrict__ C) {
  const int K = 1024, N = 1024;
  __shared__ char lds[98304];
  const int tid = threadIdx.x, lane = tid & 63, wid = tid >> 6;
  const int orig = blockIdx.x;
  const int swzb = (orig & 7) * 64 + (orig >> 3);
  const int bm = (swzb >> 2) * 256, bn = (swzb & 3) * 256;
  const int wm = wid >> 2, wn = wid & 3;

  // A staging (fp32, 4 gloads x 8KB): dest row = g*64 + wid*8 + (lane>>3),
  // chunk (lane&7); source col pre-swizzled by key = row&7 = (lane>>3)&7.
  const int srA   = wid * 8 + (lane >> 3);
  const int scolA = ((lane & 7) * 4) ^ (((lane >> 3) & 7) << 2);   // f32 elems
  const float* gA = A + (size_t)(bm + srA) * K + scolA;

  // B staging (bf16, 2 gloads x 8KB): dest row = g*128 + wid*16 + (lane>>2),
  // chunk (lane&3); key = (row>>1)&3 = (lane>>3)&3.
  const int srB   = wid * 16 + (lane >> 2);
  const int scolB = ((lane & 3) * 8) ^ (((lane >> 3) & 3) << 3);   // bf16 elems
  const unsigned short* gB = Bm + (size_t)(bn + srB) * K + scolB;
  const int dstw = wid * 1024;

  // fragment read keys
  const int aswzA = (lane & 7) << 4;                       // A rows: key row&7
  const int arow0 = (wm * 128 + (lane & 15)) * 128;        // A row base (bytes)
  const int acol0 = (lane >> 4) * 32;                      // A byte col (2 chunks)
  const int bswz  = (((lane & 15) >> 1) & 3) << 4;         // B rows: key (row>>1)&3
  const int brow0 = 32768 + (wn * 64 + (lane & 15)) * 64;  // B row base (bytes)
  const int kcB   = ((lane >> 4) * 16) ^ bswz;

  f32x4 acc[8][4];
#pragma unroll
  for (int fn = 0; fn < 4; ++fn) {
    float bv = bias[bn + wn * 64 + fn * 16 + (lane & 15)];
    f32x4 sp = {bv, bv, bv, bv};
#pragma unroll
    for (int fm = 0; fm < 8; ++fm) acc[fm][fn] = sp;
  }

  bf16x8 bF[4];

  auto stA = [&](int buf, int kt) {          // 4 gload_lds (fp32, 16B/lane)
    char* d = lds + buf * 49152 + dstw;
    const float* g = gA + kt * 32;
#pragma unroll
    for (int gg = 0; gg < 4; ++gg)
      GL2LDS(g + (size_t)(gg * 64) * K, d + gg * 8192);
  };
  auto stB = [&](int buf, int kt) {          // 2 gload_lds
    char* d = lds + buf * 49152 + 32768 + dstw;
    const unsigned short* g = gB + kt * 32;
    GL2LDS(g, d);
    GL2LDS(g + (size_t)128 * K, d + 8192);
  };
  auto loadB4 = [&](int buf) {
#pragma unroll
    for (int n = 0; n < 4; ++n)
      bF[n] = *(const bf16x8*)(lds + buf * 49152 + brow0 + n * 1024 + kcB);
  };
  auto loadAcvt = [&](int buf, int f) -> bf16x8 {
    const char* p = lds + buf * 49152 + arow0 + f * 2048;
    f32x4 lo = *(const f32x4*)(p + (acol0 ^ aswzA));
    f32x4 hi = *(const f32x4*)(p + ((acol0 + 16) ^ aswzA));
    union { unsigned int u[4]; bf16x8 v; } cv;
    asm("v_cvt_pk_bf16_f32 %0, %1, %2" : "=v"(cv.u[0]) : "v"(lo[0]), "v"(lo[1]));
    asm("v_cvt_pk_bf16_f32 %0, %1, %2" : "=v"(cv.u[1]) : "v"(lo[2]), "v"(lo[3]));
    asm("v_cvt_pk_bf16_f32 %0, %1, %2" : "=v"(cv.u[2]) : "v"(hi[0]), "v"(hi[1]));
    asm("v_cvt_pk_bf16_f32 %0, %1, %2" : "=v"(cv.u[3]) : "v"(hi[2]), "v"(hi[3]));
    return cv.v;
  };

  // prologue: stage tiles 0 and 1 (order per tile: stA then stB)
  stA(0, 0); stB(0, 0);
  stA(1, 1); stB(1, 1);
  asm volatile("s_waitcnt vmcnt(6)" ::: "memory");   // tile 0 landed
  BAR();

#define KT(t, STG, DOW, WSTR)                                 \
  {                                                           \
    const int b_ = (t) & 1;                                   \
    loadB4(b_);                                               \
    _Pragma("unroll")                                         \
    for (int f = 0; f < 8; ++f) {                             \
      bf16x8 aF = loadAcvt(b_, f);                            \
      __builtin_amdgcn_s_setprio(1);                          \
      _Pragma("unroll")                                       \
      for (int n = 0; n < 4; ++n)                             \
        acc[f][n] = __builtin_amdgcn_mfma_f32_16x16x32_bf16(aF, bF[n], acc[f][n], 0, 0, 0); \
      __builtin_amdgcn_s_setprio(0);                          \
    }                                                         \
    BAR();                                                    \
    if (STG) { stA(b_, (t) + 2); stB(b_, (t) + 2); }          \
    if (DOW) { asm volatile("s_waitcnt vmcnt(" WSTR ")" ::: "memory"); } \
    BAR();                                                    \
  }

  for (int t = 0; t < 30; ++t) KT(t, 1, 1, "6")
  KT(30, 0, 1, "0")
  KT(31, 0, 0, "0")
#undef KT

  // epilogue: C write (r8 mapping)
  const int crow0 = bm + wm * 128 + (lane >> 4) * 4;
  const int ccol0 = bn + wn * 64 + (lane & 15);
#pragma unroll
  for (int fm = 0; fm < 8; ++fm)
#pragma unroll
    for (int j = 0; j < 4; ++j) {
      unsigned short* cp = C + (size_t)(crow0 + fm * 16 + j) * N + ccol0;
#pragma unroll
      for (int fn = 0; fn < 4; ++fn) cp[fn * 16] = f2bf(acc[fm][fn][j]);
    }
}

// ---------------------------------------------------------------- phase1 (MFMA): U-partials + colsum
__global__ __launch_bounds__(256, 2) void phase1(
    const unsigned short* __restrict__ Pk,
    const unsigned short* __restrict__ Pv,
    const float* __restrict__ mask_attn,
    float* __restrict__ Upart,     // [8][64][64][64]
    float* __restrict__ cspart) {  // [8][64][64]
  const int chunk = blockIdx.x;
  const int nh = blockIdx.y;
  const int n = nh >> 4, h = nh & 15;
  const int tid = threadIdx.x, lane = tid & 63, wid = tid >> 6;
  __shared__ __align__(16) unsigned short ekT[64 * 256];  // 32 KB
  __shared__ __align__(16) unsigned short vpT[64 * 256];  // 32 KB

  f32x4 acc[5];
#pragma unroll
  for (int i = 0; i < 5; ++i) acc[i] = (f32x4){0.f, 0.f, 0.f, 0.f};
  bf16x8 ones;
#pragma unroll
  for (int j = 0; j < 8; ++j) ones[j] = (short)0x3f80;

  const int isV = tid >> 7;
  const int slot0 = tid & 127;
  const unsigned short* src = isV ? Pv : Pk;
  unsigned short* dstT = isV ? vpT : ekT;

  const int arow = wid * 16 + (lane & 15);
  const int aswz = ((arow & 7) ^ ((arow >> 3) & 7)) << 4;

  for (int stage = 0; stage < 4; ++stage) {
    if (stage) __syncthreads();
#pragma unroll
    for (int r = 0; r < 2; ++r) {
      const int slot = slot0 + r * 128;
      const int toct = slot >> 3;
      const int d0   = (slot & 7) * 8;
      const int tbase = chunk * 1024 + stage * 256 + toct * 8;
      u16x8 in[8];
#pragma unroll
      for (int s = 0; s < 8; ++s)
        in[s] = *(const u16x8*)(src + (size_t)(n * T_ + tbase + s) * H_ + h * DH + d0);
      if (!isV) {
#pragma unroll
        for (int s = 0; s < 8; ++s) {
          const float madd = -10000.f * (1.f - mask_attn[n * T_ + tbase + s]);
          u16x8 o;
#pragma unroll
          for (int j = 0; j < 8; ++j) o[j] = f2bf(__expf(bf2f(in[s][j]) + madd));
          in[s] = o;
        }
      }
#pragma unroll
      for (int i = 0; i < 8; ++i) {
        u16x8 o;
#pragma unroll
        for (int s = 0; s < 8; ++s) o[s] = in[s][i];
        const int d = d0 + i;
        const int boff = (toct * 16) ^ (((d & 7) ^ ((d >> 3) & 7)) << 4);
        *(u16x8*)((char*)dstT + d * 512 + boff) = o;
      }
    }
    __syncthreads();
#pragma unroll
    for (int kk = 0; kk < 8; ++kk) {
      const int koff = kk * 64 + (lane >> 4) * 16;
      bf16x8 af = *(const bf16x8*)((const char*)ekT + arow * 512 + (koff ^ aswz));
      acc[4] = __builtin_amdgcn_mfma_f32_16x16x32_bf16(af, ones, acc[4], 0, 0, 0);
#pragma unroll
      for (int nn = 0; nn < 4; ++nn) {
        const int brow = nn * 16 + (lane & 15);
        const int bswz = ((brow & 7) ^ ((brow >> 3) & 7)) << 4;
        bf16x8 bf_ = *(const bf16x8*)((const char*)vpT + brow * 512 + (koff ^ bswz));
        acc[nn] = __builtin_amdgcn_mfma_f32_16x16x32_bf16(af, bf_, acc[nn], 0, 0, 0);
      }
    }
  }

  const int d = wid * 16 + (lane >> 4) * 4;
  const int e = lane & 15;
  float* up = Upart + ((size_t)(chunk * 64 + nh) * 64) * 64;
#pragma unroll
  for (int nn = 0; nn < 4; ++nn)
#pragma unroll
    for (int j = 0; j < 4; ++j)
      up[(size_t)(d + j) * 64 + nn * 16 + e] = acc[nn][j];
  if (e == 0)
#pragma unroll
    for (int j = 0; j < 4; ++j)
      cspart[((size_t)chunk * 64 + nh) * 64 + d + j] = acc[4][j];
}

// ---------------------------------------------------------------- ctx build
__global__ void ctxbuild(const float* __restrict__ Upart,
                         const float* __restrict__ cspart,
                         unsigned short* __restrict__ ctxT) {  // [64 nh][64 e][64 d]
  const int nh = blockIdx.x, tid = threadIdx.x;
  __shared__ float cs[64];
  if (tid < 64) {
    float s = 0;
    for (int c = 0; c < 8; ++c) s += cspart[((size_t)c * 64 + nh) * 64 + tid];
    cs[tid] = s;
  }
  __syncthreads();
  const int d0 = (tid >> 4) * 4, e0 = (tid & 15) * 4;
#pragma unroll
  for (int i = 0; i < 4; ++i) {
    const float inv = 0.125f / cs[d0 + i];   // 1/(sqrt(64)*colsum)
#pragma unroll
    for (int j = 0; j < 4; ++j) {
      float s = 0;
      for (int c = 0; c < 8; ++c)
        s += Upart[((size_t)(c * 64 + nh) * 64 + d0 + i) * 64 + e0 + j];
      ctxT[((size_t)nh * 64 + (e0 + j)) * 64 + (d0 + i)] = f2bf(s * inv);
    }
  }
}

// ---------------------------------------------------------------- out: softmax_feat(qp) @ ctx
__global__ __launch_bounds__(256) void outk(
    const unsigned short* __restrict__ Pq,
    const unsigned short* __restrict__ ctxT,
    float* __restrict__ Out) {
  const int tb = blockIdx.x;
  const int nh = blockIdx.y;
  const int n = nh >> 4, h = nh & 15;
  const int tid = threadIdx.x, lane = tid & 63, wid = tid >> 6;
  __shared__ unsigned short sp[128][72];

  bf16x8 breg[2][4];
#pragma unroll
  for (int ks = 0; ks < 2; ++ks)
#pragma unroll
    for (int nn = 0; nn < 4; ++nn)
      breg[ks][nn] = *(const bf16x8*)(ctxT + ((size_t)nh * 64 + nn * 16 + (lane & 15)) * 64
                                      + ks * 32 + (lane >> 4) * 8);

  const int r = tid >> 1, half = tid & 1;
  const int t0 = tb * 128;
  const size_t qoff = (size_t)(n * T_ + t0 + r) * H_ + h * DH + half * 32;
  u16x8 qv[4];
#pragma unroll
  for (int s = 0; s < 4; ++s) qv[s] = *(const u16x8*)(Pq + qoff + s * 8);
  float e[32]; float sum = 0.f;
#pragma unroll
  for (int s = 0; s < 4; ++s)
#pragma unroll
    for (int j = 0; j < 8; ++j) { float x = __expf(bf2f(qv[s][j])); e[s * 8 + j] = x; sum += x; }
  sum += __shfl_xor(sum, 1);
  const float inv = 1.f / sum;
#pragma unroll
  for (int s = 0; s < 4; ++s) {
    u16x8 pb;
#pragma unroll
    for (int j = 0; j < 8; ++j) pb[j] = f2bf(e[s * 8 + j] * inv);
    *(u16x8*)&sp[r][half * 32 + s * 8] = pb;
  }
  __syncthreads();

  f32x4 acc[2][4];
  f32x4 z = {0.f, 0.f, 0.f, 0.f};
#pragma unroll
  for (int mm = 0; mm < 2; ++mm)
#pragma unroll
    for (int nn = 0; nn < 4; ++nn) acc[mm][nn] = z;
  const int wm = wid * 32;
#pragma unroll
  for (int ks = 0; ks < 2; ++ks) {
    bf16x8 av[2];
#pragma unroll
    for (int mm = 0; mm < 2; ++mm)
      av[mm] = *(const bf16x8*)((const char*)&sp[0][0]
               + (wm + mm * 16 + (lane & 15)) * 144 + ks * 64 + (lane >> 4) * 16);
#pragma unroll
    for (int mm = 0; mm < 2; ++mm)
#pragma unroll
      for (int nn = 0; nn < 4; ++nn)
        acc[mm][nn] = __builtin_amdgcn_mfma_f32_16x16x32_bf16(av[mm], breg[ks][nn], acc[mm][nn], 0, 0, 0);
  }

#pragma unroll
  for (int mm = 0; mm < 2; ++mm)
#pragma unroll
    for (int j = 0; j < 4; ++j) {
      const int row = t0 + wm + mm * 16 + (lane >> 4) * 4 + j;
      float* op = Out + ((size_t)n * T_ + row) * H_ + h * DH + (lane & 15);
#pragma unroll
      for (int nn = 0; nn < 4; ++nn) op[nn * 16] = acc[mm][nn][j];
    }
}

// ---------------------------------------------------------------- launch
extern "C" void kernel_launch(void* const* d_in, const int* in_sizes, int n_in,
                              void* d_out, int out_size, void* d_ws, size_t ws_size,
                              hipStream_t stream) {
  const float* q  = (const float*)d_in[0];
  const float* k  = (const float*)d_in[1];
  const float* v  = (const float*)d_in[2];
  // d_in[3] = mask_q: per-row constant before feature-dim softmax -> provably a no-op
  const float* mask_attn = (const float*)d_in[4];
  const float* Wq = (const float*)d_in[5];
  const float* bq = (const float*)d_in[6];
  const float* Wk = (const float*)d_in[7];
  const float* bk = (const float*)d_in[8];
  const float* Wv = (const float*)d_in[9];
  const float* bv = (const float*)d_in[10];
  float* out = (float*)d_out;

  char* ws = (char*)d_ws;
  size_t off = 0;
  unsigned short* Wb = (unsigned short*)(ws + off); off += (size_t)3 * H_ * H_ * 2;   // 6 MB
  unsigned short* Pq = (unsigned short*)(ws + off); off += (size_t)BT * H_ * 2;
  unsigned short* Pk = (unsigned short*)(ws + off); off += (size_t)BT * H_ * 2;
  unsigned short* Pv = (unsigned short*)(ws + off); off += (size_t)BT * H_ * 2;
  float* Upart  = (float*)(ws + off); off += (size_t)8 * 64 * 64 * 64 * 4;            // 8 MB
  float* cspart = (float*)(ws + off); off += (size_t)8 * 64 * 64 * 4;
  unsigned short* ctxT = (unsigned short*)(ws + off); off += (size_t)64 * 64 * 64 * 2;

  dim3 blk(256);
  const int nW4 = H_ * H_ / 4;
  cvt_kernel<<<dim3(512), blk, 0, stream>>>(Wq, Wb + 0 * H_ * H_, nW4);
  cvt_kernel<<<dim3(512), blk, 0, stream>>>(Wk, Wb + 1 * H_ * H_, nW4);
  cvt_kernel<<<dim3(512), blk, 0, stream>>>(Wv, Wb + 2 * H_ * H_, nW4);

  dim3 gblk(512);
  dim3 ggrid(512);   // 128 Mtiles x 4 Ntiles
  gemm256d<<<ggrid, gblk, 0, stream>>>(k, Wb + 1 * H_ * H_, bk, Pk);
  gemm256d<<<ggrid, gblk, 0, stream>>>(v, Wb + 2 * H_ * H_, bv, Pv);
  gemm256d<<<ggrid, gblk, 0, stream>>>(q, Wb + 0 * H_ * H_, bq, Pq);

  phase1<<<dim3(8, 64), blk, 0, stream>>>(Pk, Pv, mask_attn, Upart, cspart);
  ctxbuild<<<dim3(64), blk, 0, stream>>>(Upart, cspart, ctxT);
  outk<<<dim3(64, 64), blk, 0, stream>>>(Pq, ctxT, out);
}

// Round 12
// 405.054 us; speedup vs baseline: 1.2398x; 1.0240x over previous
//
#include <hip/hip_runtime.h>
#include <hip/hip_bf16.h>
#include <math.h>

// Problem constants
#define B_  4
#define T_  8192
#define H_  1024
#define NHEAD 16
#define DH  64
#define BT  (B_*T_)   // 32768 rows

typedef __attribute__((ext_vector_type(8))) short bf16x8;
typedef __attribute__((ext_vector_type(4))) float f32x4;
typedef __attribute__((ext_vector_type(2))) float f32x2;
typedef __attribute__((ext_vector_type(2))) unsigned short u16x2;
typedef __attribute__((ext_vector_type(4))) unsigned short u16x4;
typedef __attribute__((ext_vector_type(8))) unsigned short u16x8;

static __device__ __forceinline__ float bf2f(unsigned short u) {
  union { unsigned int i; float f; } x; x.i = ((unsigned int)u) << 16; return x.f;
}
static __device__ __forceinline__ unsigned short f2bf(float f) {
  union { float f; unsigned int i; } x; x.f = f;
  unsigned int r = x.i + 0x7fffu + ((x.i >> 16) & 1u);  // RNE
  return (unsigned short)(r >> 16);
}

#define GL2LDS(gptr, sptr) \
  __builtin_amdgcn_global_load_lds((const __attribute__((address_space(1))) void*)(gptr), \
                                   (__attribute__((address_space(3))) void*)(sptr), 16, 0, 0)

#define BAR() do { asm volatile("" ::: "memory"); __builtin_amdgcn_s_barrier(); \
                   asm volatile("" ::: "memory"); } while (0)

// ---------------------------------------------------------------- cvt fp32->bf16
__global__ void cvt_kernel(const float* __restrict__ in, unsigned short* __restrict__ out, int n4) {
  int i = blockIdx.x * blockDim.x + threadIdx.x;
  int stride = gridDim.x * blockDim.x;
  for (int idx = i; idx < n4; idx += stride) {
    float4 v = reinterpret_cast<const float4*>(in)[idx];
    u16x4 o;
    o.x = f2bf(v.x); o.y = f2bf(v.y); o.z = f2bf(v.z); o.w = f2bf(v.w);
    reinterpret_cast<u16x4*>(out)[idx] = o;
  }
}

// ---------------------------------------------------------------- 256x256 bf16 GEMM, faithful m201 8-phase
// C[M,N] = A[M,K]*B[N,K]^T + bias ; M=32768, N=K=1024. BM=BN=256, BK=64,
// 8 waves (2Mx4N), 128x64 out/wave. LDS 128KB: buf0=even K-tile, buf1=odd
// (FIXED assignment); each buf = A 32KB + B 32KB; half-tile = 128 rows(16KB)
// = 2 gload_lds.
// 8 phases per iteration (2 K-tiles). Phase = { ds-reads + issue ONE
// half-tile prefetch; [lgkmcnt(8) if 12 reads]; BAR; lgkmcnt(0)+sched_bar;
// setprio(1) 16xMFMA setprio(0); [vmcnt(4) at ph4/ph8]; BAR }.
// Reads: ph1/5 = 12 (aF mh0 + bF nh0), ph2/6 = 4 (bF nh1), ph3/7 = 8
// (aF mh1), ph4/8 = 0. Quads: (0,0)(0,1)(1,1)(1,0) - bF regs persist.
// STAGE SLOTS (iter i, t0=2i; audited write-after-last-read + landed-before-
// first-read by induction, vmcnt(4)@ph4 drains tile t0+1, @ph8 drains t0+2's
// first halves... full audit in session notes):
//  ph1: A(t0+1)h1->buf1   ph2: B(t0+1)h1->buf1  ph3: B(t0+2)h0->buf0
//  ph4: A(t0+2)h0->buf0   ph5: A(t0+2)h1->buf0  ph6: B(t0+2)h1->buf0
//  ph7: B(t0+3)h0->buf1   ph8: A(t0+3)h0->buf1
// Last iter (t0=14): stages only ph1/ph2 (A15h1,B15h1); vmcnt(0) at ph4.
// SWIZZLE (r5-verified, 0 conflicts): byte ^= ((row&7)<<4); linear gload
// dest + pre-swizzled source col; frag read col = ((lane>>4)*16+ks*64)^aswz.
// grid = 512 blocks, XCD-bijective swizzle (512%8==0).
__global__ __launch_bounds__(512, 2) void gemm256(
    const unsigned short* __restrict__ A,
    const unsigned short* __restrict__ Bm,
    const float* __restrict__ bias,
    unsigned short* __restrict__ C) {
  const int K = 1024, N = 1024;
  __shared__ char lds[131072];
  const int tid = threadIdx.x, lane = tid & 63, wid = tid >> 6;
  const int orig = blockIdx.x;
  const int swzb = (orig & 7) * 64 + (orig >> 3);
  const int bm = (swzb >> 2) * 256, bn = (swzb & 3) * 256;
  const int wm = wid >> 2, wn = wid & 3;

  // staging: lane covers linear LDS bytes (wid*1024 + lane*16) of a 64-row
  // chunk = row sr, pre-swizzled source col.
  const int sr   = wid * 8 + (lane >> 3);
  const int scol = ((lane & 7) * 8) ^ ((lane >> 3) << 3);
  const unsigned short* gA = A  + (size_t)(bm + sr) * K + scol;
  const unsigned short* gB = Bm + (size_t)(bn + sr) * K + scol;
  const int dstw = wid * 1024;

  // fragment read: col = ((lane>>4)*16 + ks*64) ^ ((lane&7)<<4)
  const int aswz  = (lane & 7) << 4;
  const int arow0 = (wm * 128 + (lane & 15)) * 128;            // A row-base bytes
  const int brow0 = 32768 + (wn * 64 + (lane & 15)) * 128;     // B row-base bytes

  f32x4 acc[8][4];
#pragma unroll
  for (int fn = 0; fn < 4; ++fn) {
    float bv = bias[bn + wn * 64 + fn * 16 + (lane & 15)];
    f32x4 sp = {bv, bv, bv, bv};
#pragma unroll
    for (int fm = 0; fm < 8; ++fm) acc[fm][fn] = sp;
  }

  bf16x8 aF[4][2], bF[4][2];

  auto stHA = [&](int buf, int kt, int h) {          // A half-tile: 2 gloads
    char* d = lds + buf * 65536 + h * 16384 + dstw;
    const unsigned short* g = gA + (size_t)(h * 128) * K + kt * 64;
    GL2LDS(g, d);
    GL2LDS(g + (size_t)64 * K, d + 8192);
  };
  auto stHB = [&](int buf, int kt, int h) {          // B half-tile: 2 gloads
    char* d = lds + buf * 65536 + 32768 + h * 16384 + dstw;
    const unsigned short* g = gB + (size_t)(h * 128) * K + kt * 64;
    GL2LDS(g, d);
    GL2LDS(g + (size_t)64 * K, d + 8192);
  };
  auto loadA = [&](int buf, int mh) {                // 8 x ds_read_b128
#pragma unroll
    for (int f = 0; f < 4; ++f)
#pragma unroll
      for (int ks = 0; ks < 2; ++ks)
        aF[f][ks] = *(const bf16x8*)(lds + buf * 65536 + arow0 + (mh * 4 + f) * 2048
                                     + (((lane >> 4) * 16 + ks * 64) ^ aswz));
  };
  auto loadB2 = [&](int buf, int nh) {               // 4 x ds_read_b128
#pragma unroll
    for (int g2 = 0; g2 < 2; ++g2)
#pragma unroll
      for (int ks = 0; ks < 2; ++ks)
        bF[nh * 2 + g2][ks] = *(const bf16x8*)(lds + buf * 65536 + brow0 + (nh * 2 + g2) * 2048
                                               + (((lane >> 4) * 16 + ks * 64) ^ aswz));
  };
  auto quad = [&](int mh, int nh) {                  // 16 MFMA (T5 setprio)
    __builtin_amdgcn_s_setprio(1);
#pragma unroll
    for (int f = 0; f < 4; ++f)
#pragma unroll
      for (int g2 = 0; g2 < 2; ++g2)
#pragma unroll
        for (int ks = 0; ks < 2; ++ks)
          acc[mh * 4 + f][nh * 2 + g2] = __builtin_amdgcn_mfma_f32_16x16x32_bf16(
              aF[f][ks], bF[nh * 2 + g2][ks], acc[mh * 4 + f][nh * 2 + g2], 0, 0, 0);
    __builtin_amdgcn_s_setprio(0);
  };

// PHASE: READS/STAGE are statements (commas only inside parens).
#define PHASE(READS, STAGE, LGKM8, DOVM, VMSTR, MH, NH)       \
  {                                                           \
    READS;                                                    \
    STAGE;                                                    \
    if (LGKM8) asm volatile("s_waitcnt lgkmcnt(8)" ::: "memory"); \
    BAR();                                                    \
    asm volatile("s_waitcnt lgkmcnt(0)" ::: "memory");        \
    __builtin_amdgcn_sched_barrier(0);                        \
    quad(MH, NH);                                             \
    if (DOVM) asm volatile("s_waitcnt vmcnt(" VMSTR ")" ::: "memory"); \
    BAR();                                                    \
  }

  // prologue: tile0 (buf0) full + tile1 (buf1) B-h0, A-h0 = 12 loads;
  // vmcnt(4) drains tile0's 8; remaining 4 = B1h0, A1h0.
  stHA(0, 0, 0); stHA(0, 0, 1); stHB(0, 0, 0); stHB(0, 0, 1);
  stHB(1, 1, 0); stHA(1, 1, 0);
  asm volatile("s_waitcnt vmcnt(4)" ::: "memory");
  BAR();

  for (int it = 0; it < 7; ++it) {
    const int t0 = 2 * it;
    PHASE(loadA(0, 0); loadB2(0, 0), stHA(1, t0 + 1, 1), 1, 0, "4", 0, 0)
    PHASE(loadB2(0, 1),              stHB(1, t0 + 1, 1), 0, 0, "4", 0, 1)
    PHASE(loadA(0, 1),               stHB(0, t0 + 2, 0), 0, 0, "4", 1, 1)
    PHASE((void)0,                   stHA(0, t0 + 2, 0), 0, 1, "4", 1, 0)
    PHASE(loadA(1, 0); loadB2(1, 0), stHA(0, t0 + 2, 1), 1, 0, "4", 0, 0)
    PHASE(loadB2(1, 1),              stHB(0, t0 + 2, 1), 0, 0, "4", 0, 1)
    PHASE(loadA(1, 1),               stHB(1, t0 + 3, 0), 0, 0, "4", 1, 1)
    PHASE((void)0,                   stHA(1, t0 + 3, 0), 0, 1, "4", 1, 0)
  }
  // last iteration (tiles 14,15): stages only ph1/ph2; drain at ph4.
  PHASE(loadA(0, 0); loadB2(0, 0), stHA(1, 15, 1), 1, 0, "4", 0, 0)
  PHASE(loadB2(0, 1),              stHB(1, 15, 1), 0, 0, "4", 0, 1)
  PHASE(loadA(0, 1),               (void)0,        0, 0, "4", 1, 1)
  PHASE((void)0,                   (void)0,        0, 1, "0", 1, 0)
  PHASE(loadA(1, 0); loadB2(1, 0), (void)0,        1, 0, "4", 0, 0)
  PHASE(loadB2(1, 1),              (void)0,        0, 0, "4", 0, 1)
  PHASE(loadA(1, 1),               (void)0,        0, 0, "4", 1, 1)
  PHASE((void)0,                   (void)0,        0, 0, "4", 1, 0)
#undef PHASE

  // epilogue: C write
  const int crow0 = bm + wm * 128 + (lane >> 4) * 4;
  const int ccol0 = bn + wn * 64 + (lane & 15);
#pragma unroll
  for (int fm = 0; fm < 8; ++fm)
#pragma unroll
    for (int j = 0; j < 4; ++j) {
      unsigned short* cp = C + (size_t)(crow0 + fm * 16 + j) * N + ccol0;
#pragma unroll
      for (int fn = 0; fn < 4; ++fn) cp[fn * 16] = f2bf(acc[fm][fn][j]);
    }
}

// ---------------------------------------------------------------- phase1 (MFMA): U-partials + colsum
__global__ __launch_bounds__(256, 2) void phase1(
    const unsigned short* __restrict__ Pk,
    const unsigned short* __restrict__ Pv,
    const float* __restrict__ mask_attn,
    float* __restrict__ Upart,     // [8][64][64][64]
    float* __restrict__ cspart) {  // [8][64][64]
  const int chunk = blockIdx.x;
  const int nh = blockIdx.y;
  const int n = nh >> 4, h = nh & 15;
  const int tid = threadIdx.x, lane = tid & 63, wid = tid >> 6;
  __shared__ __align__(16) unsigned short ekT[64 * 256];  // 32 KB
  __shared__ __align__(16) unsigned short vpT[64 * 256];  // 32 KB

  f32x4 acc[5];
#pragma unroll
  for (int i = 0; i < 5; ++i) acc[i] = (f32x4){0.f, 0.f, 0.f, 0.f};
  bf16x8 ones;
#pragma unroll
  for (int j = 0; j < 8; ++j) ones[j] = (short)0x3f80;

  const int isV = tid >> 7;
  const int slot0 = tid & 127;
  const unsigned short* src = isV ? Pv : Pk;
  unsigned short* dstT = isV ? vpT : ekT;

  const int arow = wid * 16 + (lane & 15);
  const int aswz = ((arow & 7) ^ ((arow >> 3) & 7)) << 4;

  for (int stage = 0; stage < 4; ++stage) {
    if (stage) __syncthreads();
#pragma unroll
    for (int r = 0; r < 2; ++r) {
      const int slot = slot0 + r * 128;
      const int toct = slot >> 3;
      const int d0   = (slot & 7) * 8;
      const int tbase = chunk * 1024 + stage * 256 + toct * 8;
      u16x8 in[8];
#pragma unroll
      for (int s = 0; s < 8; ++s)
        in[s] = *(const u16x8*)(src + (size_t)(n * T_ + tbase + s) * H_ + h * DH + d0);
      if (!isV) {
#pragma unroll
        for (int s = 0; s < 8; ++s) {
          const float madd = -10000.f * (1.f - mask_attn[n * T_ + tbase + s]);
          u16x8 o;
#pragma unroll
          for (int j = 0; j < 8; ++j) o[j] = f2bf(__expf(bf2f(in[s][j]) + madd));
          in[s] = o;
        }
      }
#pragma unroll
      for (int i = 0; i < 8; ++i) {
        u16x8 o;
#pragma unroll
        for (int s = 0; s < 8; ++s) o[s] = in[s][i];
        const int d = d0 + i;
        const int boff = (toct * 16) ^ (((d & 7) ^ ((d >> 3) & 7)) << 4);
        *(u16x8*)((char*)dstT + d * 512 + boff) = o;
      }
    }
    __syncthreads();
#pragma unroll
    for (int kk = 0; kk < 8; ++kk) {
      const int koff = kk * 64 + (lane >> 4) * 16;
      bf16x8 af = *(const bf16x8*)((const char*)ekT + arow * 512 + (koff ^ aswz));
      acc[4] = __builtin_amdgcn_mfma_f32_16x16x32_bf16(af, ones, acc[4], 0, 0, 0);
#pragma unroll
      for (int nn = 0; nn < 4; ++nn) {
        const int brow = nn * 16 + (lane & 15);
        const int bswz = ((brow & 7) ^ ((brow >> 3) & 7)) << 4;
        bf16x8 bf_ = *(const bf16x8*)((const char*)vpT + brow * 512 + (koff ^ bswz));
        acc[nn] = __builtin_amdgcn_mfma_f32_16x16x32_bf16(af, bf_, acc[nn], 0, 0, 0);
      }
    }
  }

  const int d = wid * 16 + (lane >> 4) * 4;
  const int e = lane & 15;
  float* up = Upart + ((size_t)(chunk * 64 + nh) * 64) * 64;
#pragma unroll
  for (int nn = 0; nn < 4; ++nn)
#pragma unroll
    for (int j = 0; j < 4; ++j)
      up[(size_t)(d + j) * 64 + nn * 16 + e] = acc[nn][j];
  if (e == 0)
#pragma unroll
    for (int j = 0; j < 4; ++j)
      cspart[((size_t)chunk * 64 + nh) * 64 + d + j] = acc[4][j];
}

// ---------------------------------------------------------------- ctx build
__global__ void ctxbuild(const float* __restrict__ Upart,
                         const float* __restrict__ cspart,
                         unsigned short* __restrict__ ctxT) {  // [64 nh][64 e][64 d]
  const int nh = blockIdx.x, tid = threadIdx.x;
  __shared__ float cs[64];
  if (tid < 64) {
    float s = 0;
    for (int c = 0; c < 8; ++c) s += cspart[((size_t)c * 64 + nh) * 64 + tid];
    cs[tid] = s;
  }
  __syncthreads();
  const int d0 = (tid >> 4) * 4, e0 = (tid & 15) * 4;
#pragma unroll
  for (int i = 0; i < 4; ++i) {
    const float inv = 0.125f / cs[d0 + i];   // 1/(sqrt(64)*colsum)
#pragma unroll
    for (int j = 0; j < 4; ++j) {
      float s = 0;
      for (int c = 0; c < 8; ++c)
        s += Upart[((size_t)(c * 64 + nh) * 64 + d0 + i) * 64 + e0 + j];
      ctxT[((size_t)nh * 64 + (e0 + j)) * 64 + (d0 + i)] = f2bf(s * inv);
    }
  }
}

// ---------------------------------------------------------------- out: softmax_feat(qp) @ ctx
__global__ __launch_bounds__(256) void outk(
    const unsigned short* __restrict__ Pq,
    const unsigned short* __restrict__ ctxT,
    float* __restrict__ Out) {
  const int tb = blockIdx.x;
  const int nh = blockIdx.y;
  const int n = nh >> 4, h = nh & 15;
  const int tid = threadIdx.x, lane = tid & 63, wid = tid >> 6;
  __shared__ unsigned short sp[128][72];

  bf16x8 breg[2][4];
#pragma unroll
  for (int ks = 0; ks < 2; ++ks)
#pragma unroll
    for (int nn = 0; nn < 4; ++nn)
      breg[ks][nn] = *(const bf16x8*)(ctxT + ((size_t)nh * 64 + nn * 16 + (lane & 15)) * 64
                                      + ks * 32 + (lane >> 4) * 8);

  const int r = tid >> 1, half = tid & 1;
  const int t0 = tb * 128;
  const size_t qoff = (size_t)(n * T_ + t0 + r) * H_ + h * DH + half * 32;
  u16x8 qv[4];
#pragma unroll
  for (int s = 0; s < 4; ++s) qv[s] = *(const u16x8*)(Pq + qoff + s * 8);
  float e[32]; float sum = 0.f;
#pragma unroll
  for (int s = 0; s < 4; ++s)
#pragma unroll
    for (int j = 0; j < 8; ++j) { float x = __expf(bf2f(qv[s][j])); e[s * 8 + j] = x; sum += x; }
  sum += __shfl_xor(sum, 1);
  const float inv = 1.f / sum;
#pragma unroll
  for (int s = 0; s < 4; ++s) {
    u16x8 pb;
#pragma unroll
    for (int j = 0; j < 8; ++j) pb[j] = f2bf(e[s * 8 + j] * inv);
    *(u16x8*)&sp[r][half * 32 + s * 8] = pb;
  }
  __syncthreads();

  f32x4 acc[2][4];
  f32x4 z = {0.f, 0.f, 0.f, 0.f};
#pragma unroll
  for (int mm = 0; mm < 2; ++mm)
#pragma unroll
    for (int nn = 0; nn < 4; ++nn) acc[mm][nn] = z;
  const int wm = wid * 32;
#pragma unroll
  for (int ks = 0; ks < 2; ++ks) {
    bf16x8 av[2];
#pragma unroll
    for (int mm = 0; mm < 2; ++mm)
      av[mm] = *(const bf16x8*)((const char*)&sp[0][0]
               + (wm + mm * 16 + (lane & 15)) * 144 + ks * 64 + (lane >> 4) * 16);
#pragma unroll
    for (int mm = 0; mm < 2; ++mm)
#pragma unroll
      for (int nn = 0; nn < 4; ++nn)
        acc[mm][nn] = __builtin_amdgcn_mfma_f32_16x16x32_bf16(av[mm], breg[ks][nn], acc[mm][nn], 0, 0, 0);
  }

#pragma unroll
  for (int mm = 0; mm < 2; ++mm)
#pragma unroll
    for (int j = 0; j < 4; ++j) {
      const int row = t0 + wm + mm * 16 + (lane >> 4) * 4 + j;
      float* op = Out + ((size_t)n * T_ + row) * H_ + h * DH + (lane & 15);
#pragma unroll
      for (int nn = 0; nn < 4; ++nn) op[nn * 16] = acc[mm][nn][j];
    }
}

// ---------------------------------------------------------------- launch
extern "C" void kernel_launch(void* const* d_in, const int* in_sizes, int n_in,
                              void* d_out, int out_size, void* d_ws, size_t ws_size,
                              hipStream_t stream) {
  const float* q  = (const float*)d_in[0];
  const float* k  = (const float*)d_in[1];
  const float* v  = (const float*)d_in[2];
  // d_in[3] = mask_q: per-row constant before feature-dim softmax -> provably a no-op
  const float* mask_attn = (const float*)d_in[4];
  const float* Wq = (const float*)d_in[5];
  const float* bq = (const float*)d_in[6];
  const float* Wk = (const float*)d_in[7];
  const float* bk = (const float*)d_in[8];
  const float* Wv = (const float*)d_in[9];
  const float* bv = (const float*)d_in[10];
  float* out = (float*)d_out;

  char* ws = (char*)d_ws;
  size_t off = 0;
  unsigned short* Xb = (unsigned short*)(ws + off); off += (size_t)BT * H_ * 2;       // 64 MB
  unsigned short* Wb = (unsigned short*)(ws + off); off += (size_t)3 * H_ * H_ * 2;   // 6 MB
  unsigned short* Pq = (unsigned short*)(ws + off); off += (size_t)BT * H_ * 2;
  unsigned short* Pk = (unsigned short*)(ws + off); off += (size_t)BT * H_ * 2;
  unsigned short* Pv = (unsigned short*)(ws + off); off += (size_t)BT * H_ * 2;
  float* Upart  = (float*)(ws + off); off += (size_t)8 * 64 * 64 * 64 * 4;            // 8 MB
  float* cspart = (float*)(ws + off); off += (size_t)8 * 64 * 64 * 4;
  unsigned short* ctxT = (unsigned short*)(ws + off); off += (size_t)64 * 64 * 64 * 2;

  dim3 blk(256);
  const int nW4 = H_ * H_ / 4;
  cvt_kernel<<<dim3(512), blk, 0, stream>>>(Wq, Wb + 0 * H_ * H_, nW4);
  cvt_kernel<<<dim3(512), blk, 0, stream>>>(Wk, Wb + 1 * H_ * H_, nW4);
  cvt_kernel<<<dim3(512), blk, 0, stream>>>(Wv, Wb + 2 * H_ * H_, nW4);

  const int nX4 = BT * H_ / 4;
  dim3 gblk(512);
  dim3 ggrid(512);   // 128 Mtiles x 4 Ntiles
  cvt_kernel<<<dim3(2048), blk, 0, stream>>>(k, Xb, nX4);
  gemm256<<<ggrid, gblk, 0, stream>>>(Xb, Wb + 1 * H_ * H_, bk, Pk);
  cvt_kernel<<<dim3(2048), blk, 0, stream>>>(v, Xb, nX4);
  gemm256<<<ggrid, gblk, 0, stream>>>(Xb, Wb + 2 * H_ * H_, bv, Pv);
  cvt_kernel<<<dim3(2048), blk, 0, stream>>>(q, Xb, nX4);
  gemm256<<<ggrid, gblk, 0, stream>>>(Xb, Wb + 0 * H_ * H_, bq, Pq);

  phase1<<<dim3(8, 64), blk, 0, stream>>>(Pk, Pv, mask_attn, Upart, cspart);
  ctxbuild<<<dim3(64), blk, 0, stream>>>(Upart, cspart, ctxT);
  outk<<<dim3(64, 64), blk, 0, stream>>>(Pq, ctxT, out);
}